// Round 2
// baseline (458.456 us; speedup 1.0000x reference)
//
#include <hip/hip_runtime.h>

// TranslationRotationLoss: out = mean((tp-tt)^2 over Bx3) + mean((2*acos(clip(|dot(qp_hat,qt_hat)|,0,1)))^2 over B)
// Inputs: prediction (B,7) fp32, target (B,7) fp32. Output: 1 fp32 scalar.
// Memory-bound (470 MB read), ZERO data reuse.
// R4: drop LDS staging entirely (Common-mistake #7: staging without reuse is pure
// overhead). R3 showed occupancy 18->45% with no perf change -> not latency-bound;
// the stage->vmcnt(0)drain->barrier cycle structure was the suspect. Direct
// per-thread loads: each thread owns 4 rows = 7 contiguous float4 (112 B) per array.
// 14 independent global_load_dwordx4 in flight per thread, no barriers, no LDS.
// Every 128B line is fully consumed (dense), so HBM-side traffic is identical to
// the coalesced version; only intra-CU request count rises (>=2x headroom vs the
// 10 B/cy/CU HBM share). This is the structure class that measures 4.9-6.3 TB/s.

#define BLOCK 256

__global__ __launch_bounds__(BLOCK, 5) void trl_partial_kernel(
    const float* __restrict__ pred,
    const float* __restrict__ targ,
    float* __restrict__ partial,
    int ngroups4,         // B/4 (number of 4-row groups)
    int tail_start,       // ngroups4*4 (first leftover row, == B when B%4==0)
    int B,
    float inv3B,          // 1/(3B)
    float invB)           // 1/B
{
    const float4* __restrict__ p4 = (const float4*)pred;
    const float4* __restrict__ t4 = (const float4*)targ;

    const int gid = blockIdx.x * BLOCK + threadIdx.x;
    const int stride = gridDim.x * BLOCK;

    float tsum = 0.0f;  // sum of squared translation diffs
    float rsum = 0.0f;  // sum of angle^2

    for (int g = gid; g < ngroups4; g += stride) {
        const long b = 7L * g;          // first float4 of this thread's 4 rows
        float4 pa[7], ta[7];
#pragma unroll
        for (int k = 0; k < 7; ++k) pa[k] = p4[b + k];
#pragma unroll
        for (int k = 0; k < 7; ++k) ta[k] = t4[b + k];

        const float* pv = (const float*)pa;
        const float* tv = (const float*)ta;
#pragma unroll
        for (int j = 0; j < 4; ++j) {
            const float* p = pv + 7 * j;
            const float* t = tv + 7 * j;

            float d0 = p[0] - t[0];
            float d1 = p[1] - t[1];
            float d2 = p[2] - t[2];
            tsum += d0 * d0 + d1 * d1 + d2 * d2;

            float np2 = p[3] * p[3] + p[4] * p[4] + p[5] * p[5] + p[6] * p[6];
            float nt2 = t[3] * t[3] + t[4] * t[4] + t[5] * t[5] + t[6] * t[6];
            float dot = p[3] * t[3] + p[4] * t[4] + p[5] * t[5] + p[6] * t[6];
            float c = fabsf(dot) * rsqrtf(np2 * nt2);
            c = fminf(c, 1.0f);
            float ang = 2.0f * acosf(c);
            rsum += ang * ang;
        }
    }

    // --- leftover rows (B % 4 != 0): block 0, scalar path (tiny) ---
    if (blockIdx.x == 0) {
        for (int r = tail_start + threadIdx.x; r < B; r += BLOCK) {
            const long b = 7L * r;
            float p[7], t[7];
#pragma unroll
            for (int k = 0; k < 7; ++k) p[k] = pred[b + k];
#pragma unroll
            for (int k = 0; k < 7; ++k) t[k] = targ[b + k];
            float d0 = p[0] - t[0], d1 = p[1] - t[1], d2 = p[2] - t[2];
            tsum += d0 * d0 + d1 * d1 + d2 * d2;
            float np2 = p[3]*p[3] + p[4]*p[4] + p[5]*p[5] + p[6]*p[6];
            float nt2 = t[3]*t[3] + t[4]*t[4] + t[5]*t[5] + t[6]*t[6];
            float dot = p[3]*t[3] + p[4]*t[4] + p[5]*t[5] + p[6]*t[6];
            float c = fminf(fabsf(dot) * rsqrtf(np2 * nt2), 1.0f);
            float ang = 2.0f * acosf(c);
            rsum += ang * ang;
        }
    }

    float local = tsum * inv3B + rsum * invB;

#pragma unroll
    for (int off = 32; off > 0; off >>= 1)
        local += __shfl_down(local, off, 64);

    __shared__ float sdata[4];
    int lane = threadIdx.x & 63;
    int wave = threadIdx.x >> 6;
    if (lane == 0) sdata[wave] = local;
    __syncthreads();
    if (threadIdx.x == 0)
        partial[blockIdx.x] = sdata[0] + sdata[1] + sdata[2] + sdata[3];
}

__global__ __launch_bounds__(256) void trl_final_kernel(
    const float* __restrict__ partial, int n, float* __restrict__ out)
{
    float s = 0.0f;
    for (int i = threadIdx.x; i < n; i += 256) s += partial[i];
#pragma unroll
    for (int off = 32; off > 0; off >>= 1)
        s += __shfl_down(s, off, 64);
    __shared__ float sd[4];
    if ((threadIdx.x & 63) == 0) sd[threadIdx.x >> 6] = s;
    __syncthreads();
    if (threadIdx.x == 0) out[0] = sd[0] + sd[1] + sd[2] + sd[3];
}

extern "C" void kernel_launch(void* const* d_in, const int* in_sizes, int n_in,
                              void* d_out, int out_size, void* d_ws, size_t ws_size,
                              hipStream_t stream) {
    const float* pred = (const float*)d_in[0];
    const float* targ = (const float*)d_in[1];
    float* out = (float*)d_out;
    float* partial = (float*)d_ws;

    long long total = in_sizes[0];      // B * 7
    int B = (int)(total / 7);           // 8388608
    int ngroups4 = B / 4;               // 2097152
    int tail_start = ngroups4 * 4;      // == B here

    float invB  = 1.0f / (float)B;
    float inv3B = invB / 3.0f;

    // 2048 blocks * 256 threads = 524288 threads, each exactly 4 groups for this B.
    // Interleaved grid-stride -> the active device-wide read window sweeps the
    // arrays quasi-sequentially (DRAM-friendly).
    const int grid = 2048;

    trl_partial_kernel<<<grid, BLOCK, 0, stream>>>(pred, targ, partial, ngroups4, tail_start, B, inv3B, invB);
    trl_final_kernel<<<1, BLOCK, 0, stream>>>(partial, grid, out);
}